// Round 2
// baseline (42073.904 us; speedup 1.0000x reference)
//
#include <hip/hip_runtime.h>
#include <stdint.h>

// LSTM, E=2048, B=2, T=2048, ALL I/O float32 (per reference dtypes).
// Key identity: for t>=1 input==h, so gates = h @ (W_ih+W_hh)^T + (b_ih+b_hh).
// Wc = bf16(W_ih+W_hh) lives in LDS (128.5 KB/CU), resident across all steps.
// 256 blocks (1/CU) x 512 threads, cooperative persistent kernel with a
// two-level atomic barrier per step. h exchanged in fp32 via d_ws.
// seq (h history, fp32) written straight into d_out; projection runs in place.

#define E 2048
#define NBLK 256
#define NTHR 512
#define WSTRIDE 1028          // dwords per LDS weight row: 2048 bf16 + pad (257*16B: stride/4 odd)
#define SMEM_MAIN 152256
#define SMEM_PROJ 131072

typedef unsigned short u16;
typedef uint32_t u32;

__device__ __forceinline__ float lo16(u32 u){ return __uint_as_float(u << 16); }
__device__ __forceinline__ float hi16(u32 u){ return __uint_as_float(u & 0xffff0000u); }
__device__ __forceinline__ u16 f2bf(float f){
  u32 u = __float_as_uint(f);
  u32 r = u + 0x7fffu + ((u >> 16) & 1u);   // RNE
  return (u16)(r >> 16);
}
__device__ __forceinline__ u32 pack2(float a, float b){
  return (u32)f2bf(a) | ((u32)f2bf(b) << 16);
}
__device__ __forceinline__ float sigf(float x){ return 1.0f / (1.0f + __expf(-x)); }

// 8 bf16 weights (uint4 of packed pairs) x fp32 h (LDS) for both batches
__device__ __forceinline__ void accum8(uint4 wq, const float* __restrict__ hp,
                                       float& a0, float& a1){
  float4 p0 = *(const float4*)(hp);
  float4 p1 = *(const float4*)(hp + 4);
  float4 q0 = *(const float4*)(hp + 2048);
  float4 q1 = *(const float4*)(hp + 2052);
  float w0 = lo16(wq.x), w1 = hi16(wq.x), w2 = lo16(wq.y), w3 = hi16(wq.y);
  float w4 = lo16(wq.z), w5 = hi16(wq.z), w6 = lo16(wq.w), w7 = hi16(wq.w);
  a0 = fmaf(w0, p0.x, a0); a0 = fmaf(w1, p0.y, a0);
  a0 = fmaf(w2, p0.z, a0); a0 = fmaf(w3, p0.w, a0);
  a0 = fmaf(w4, p1.x, a0); a0 = fmaf(w5, p1.y, a0);
  a0 = fmaf(w6, p1.z, a0); a0 = fmaf(w7, p1.w, a0);
  a1 = fmaf(w0, q0.x, a1); a1 = fmaf(w1, q0.y, a1);
  a1 = fmaf(w2, q0.z, a1); a1 = fmaf(w3, q0.w, a1);
  a1 = fmaf(w4, q1.x, a1); a1 = fmaf(w5, q1.y, a1);
  a1 = fmaf(w6, q1.z, a1); a1 = fmaf(w7, q1.w, a1);
}

// 8 fp32 weights x fp32 h (t==0 path, full precision)
__device__ __forceinline__ void accum8f(float4 w0v, float4 w1v,
                                        const float* __restrict__ hp,
                                        float& a0, float& a1){
  float4 p0 = *(const float4*)(hp);
  float4 p1 = *(const float4*)(hp + 4);
  float4 q0 = *(const float4*)(hp + 2048);
  float4 q1 = *(const float4*)(hp + 2052);
  a0 = fmaf(w0v.x, p0.x, a0); a0 = fmaf(w0v.y, p0.y, a0);
  a0 = fmaf(w0v.z, p0.z, a0); a0 = fmaf(w0v.w, p0.w, a0);
  a0 = fmaf(w1v.x, p1.x, a0); a0 = fmaf(w1v.y, p1.y, a0);
  a0 = fmaf(w1v.z, p1.z, a0); a0 = fmaf(w1v.w, p1.w, a0);
  a1 = fmaf(w0v.x, q0.x, a1); a1 = fmaf(w0v.y, q0.y, a1);
  a1 = fmaf(w0v.z, q0.z, a1); a1 = fmaf(w0v.w, q0.w, a1);
  a1 = fmaf(w1v.x, q1.x, a1); a1 = fmaf(w1v.y, q1.y, a1);
  a1 = fmaf(w1v.z, q1.z, a1); a1 = fmaf(w1v.w, q1.w, a1);
}

__global__ void init_kernel(int* root, int* leaf){
  const int i = blockIdx.x * blockDim.x + threadIdx.x;
  if (i < 2048)  root[i] = 0;
  if (i < 32768) leaf[i] = 0;
}

__global__ void __launch_bounds__(NTHR, 1) lstm_kernel(
    const float* __restrict__ xin, const float* __restrict__ Wih,
    const float* __restrict__ Whh, const float* __restrict__ bih,
    const float* __restrict__ bhh, float* __restrict__ hbuf,
    int* __restrict__ root, int* __restrict__ leaf,
    float* __restrict__ seqout)
{
  extern __shared__ char smem[];
  u32*   wlds = (u32*)smem;                    // 32 rows x 1028 dw = 131584 B
  float* hlds = (float*)(smem + 131584);       // h (or x) fp32 [2][2048] = 16384 B
  float* pls  = (float*)(smem + 147968);       // partials [8][64][2] = 4096 B
  float* bias = (float*)(smem + 152064);       // [32]
  float* cst  = (float*)(smem + 152192);       // c state [2][8]

  const int tid = threadIdx.x;
  const int blk = blockIdx.x;
  const int e0  = blk << 3;                    // this block owns h elems e0..e0+7

  // ---- build Wc = bf16(Wih + Whh) into LDS: row r = gate*8 + eoff ----
  for (int idx = tid; idx < 8192; idx += NTHR){
    const int rr = idx >> 8;
    const int kc = (idx & 255) << 3;
    const int grow = ((rr >> 3) << 11) + e0 + (rr & 7);
    const float* pa = Wih + (size_t)grow * E + kc;
    const float* pb = Whh + (size_t)grow * E + kc;
    float4 a0 = *(const float4*)(pa);
    float4 a1 = *(const float4*)(pa + 4);
    float4 b0 = *(const float4*)(pb);
    float4 b1 = *(const float4*)(pb + 4);
    uint4 o;
    o.x = pack2(a0.x + b0.x, a0.y + b0.y);
    o.y = pack2(a0.z + b0.z, a0.w + b0.w);
    o.z = pack2(a1.x + b1.x, a1.y + b1.y);
    o.w = pack2(a1.z + b1.z, a1.w + b1.w);
    *(uint4*)(wlds + rr * WSTRIDE + (kc >> 1)) = o;
  }
  if (tid < 32){
    const int grow = ((tid >> 3) << 11) + e0 + (tid & 7);
    bias[tid] = bih[grow] + bhh[grow];
  }
  if (tid < 16) cst[tid] = 0.0f;
  for (int i = tid; i < 2 * E; i += NTHR) hlds[i] = xin[i];  // x for t=0
  __syncthreads();

  const int lane = tid & 63;
  const int wv   = tid >> 6;                   // wave 0..7
  const int r    = lane & 31;                  // row within block (gate*8+eoff)
  const int kh   = lane >> 5;                  // k-half within wave
  const int kbase = ((wv << 1) + kh) << 7;     // 16 k-slices x 128
  const int grow_r  = ((r >> 3) << 11) + e0 + (r & 7);
  const int leafIdx = (blk >> 4) * 2048;       // 16 groups of 16 blocks

  for (int t = 0; t < 2048; ++t){
    float a0 = 0.0f, a1 = 0.0f;
    if (t == 0){                               // step 0: x @ W_ih^T (h=0), f32 weights
      const float* wsrc = Wih + (size_t)grow_r * E + kbase;
      const float* hp = hlds + kbase;
      #pragma unroll
      for (int c = 0; c < 16; ++c){
        float4 w0v = *(const float4*)(wsrc + (c << 3));
        float4 w1v = *(const float4*)(wsrc + (c << 3) + 4);
        accum8f(w0v, w1v, hp + (c << 3), a0, a1);
      }
    } else {                                   // t>=1: h @ Wc^T from LDS (bf16 weights)
      const u32* wrow = wlds + r * WSTRIDE + (kbase >> 1);
      const float* hp = hlds + kbase;
      #pragma unroll
      for (int c = 0; c < 16; ++c){
        uint4 wq = *(const uint4*)(wrow + (c << 2));
        accum8(wq, hp + (c << 3), a0, a1);
      }
    }
    *(float2*)(pls + (((wv << 6) + lane) << 1)) = make_float2(a0, a1);
    __syncthreads();                           // (A)

    if (wv == 0){
      const int b = kh;                        // batch for reduction lane
      float s = bias[r];
      #pragma unroll
      for (int ww = 0; ww < 8; ++ww){
        s += pls[(((ww << 6) + r)      << 1) + b]
           + pls[(((ww << 6) + 32 + r) << 1) + b];
      }
      const float gi = s;
      const float gf = __shfl(s, (lane + 8)  & 63, 64);
      const float gg = __shfl(s, (lane + 16) & 63, 64);
      const float go = __shfl(s, (lane + 24) & 63, 64);
      if (r < 8){                              // lanes holding the i-gate do the update
        const int ci = (b << 3) + r;
        const float cold = cst[ci];
        const float cn = sigf(gf) * cold + sigf(gi) * tanhf(gg);
        const float hn = sigf(go) * tanhf(cn);
        cst[ci] = cn;
        const int e = e0 + r;
        __hip_atomic_store(&hbuf[((((t + 1) & 1) << 1) + b) * E + e], hn,
                           __ATOMIC_RELAXED, __HIP_MEMORY_SCOPE_AGENT);
        seqout[(((size_t)b << 11) + (size_t)t) * E + e] = hn;
      }
      if (t < 2047){
        __threadfence();                       // order h stores before arrival
        if (tid == 0){
          const int old = __hip_atomic_fetch_add(&leaf[leafIdx + t], 1,
                              __ATOMIC_ACQ_REL, __HIP_MEMORY_SCOPE_AGENT);
          if (old == 15)
            __hip_atomic_fetch_add(&root[t], 1,
                __ATOMIC_ACQ_REL, __HIP_MEMORY_SCOPE_AGENT);
          while (__hip_atomic_load(&root[t], __ATOMIC_ACQUIRE,
                                   __HIP_MEMORY_SCOPE_AGENT) < 16)
            __builtin_amdgcn_s_sleep(2);
        }
      }
    }
    __syncthreads();                           // (B) everyone waits on thread0's spin
    if (t < 2047){                             // restage fresh h into LDS
      const float* src = hbuf + (((t + 1) & 1) << 12);
      #pragma unroll
      for (int i = 0; i < 8; ++i){
        hlds[tid + (i << 9)] = __hip_atomic_load(&src[tid + (i << 9)],
                                  __ATOMIC_RELAXED, __HIP_MEMORY_SCOPE_AGENT);
      }
      __syncthreads();                         // (C)
    }
  }
}

// In-place projection: out[row][n] = sum_k h[row][k]*Wout[n][k] + bout[n].
// Block owns 16 rows: stages them (fp32) to LDS before overwriting. No
// cross-block row sharing -> race-free in place.
__global__ void __launch_bounds__(256, 1) proj_kernel(
    float* __restrict__ io, const float* __restrict__ Wout,
    const float* __restrict__ bout)
{
  extern __shared__ char smem[];
  float* alds = (float*)smem;                  // 16 x 2048 fp32 = 131072 B
  const int tid = threadIdx.x;
  const size_t rbase = (size_t)blockIdx.x * 16 * E;

  for (int idx = tid; idx < 8192; idx += 256){
    float4 v = *(const float4*)(io + rbase + ((size_t)idx << 2));
    *(float4*)(alds + (idx << 2)) = v;
  }
  __syncthreads();

  for (int p = 0; p < 8; ++p){
    const int n = (p << 8) + tid;
    const float* wrow = Wout + (size_t)n * E;
    float acc[16];
    #pragma unroll
    for (int m = 0; m < 16; ++m) acc[m] = 0.0f;
    for (int kc = 0; kc < 256; ++kc){
      const float4 w0v = *(const float4*)(wrow + (kc << 3));
      const float4 w1v = *(const float4*)(wrow + (kc << 3) + 4);
      const float* ap = alds + (kc << 3);
      #pragma unroll
      for (int m = 0; m < 16; ++m){
        const float* a = ap + (m << 11);
        float4 x0 = *(const float4*)(a);
        float4 x1 = *(const float4*)(a + 4);
        acc[m] = fmaf(w0v.x, x0.x, acc[m]); acc[m] = fmaf(w0v.y, x0.y, acc[m]);
        acc[m] = fmaf(w0v.z, x0.z, acc[m]); acc[m] = fmaf(w0v.w, x0.w, acc[m]);
        acc[m] = fmaf(w1v.x, x1.x, acc[m]); acc[m] = fmaf(w1v.y, x1.y, acc[m]);
        acc[m] = fmaf(w1v.z, x1.z, acc[m]); acc[m] = fmaf(w1v.w, x1.w, acc[m]);
      }
    }
    const float bo = bout[n];
    #pragma unroll
    for (int m = 0; m < 16; ++m)
      io[rbase + ((size_t)m << 11) + n] = acc[m] + bo;
  }
}

extern "C" void kernel_launch(void* const* d_in, const int* in_sizes, int n_in,
                              void* d_out, int out_size, void* d_ws, size_t ws_size,
                              hipStream_t stream)
{
  const float* xin  = (const float*)d_in[0];
  const float* Wih  = (const float*)d_in[1];
  const float* Whh  = (const float*)d_in[2];
  const float* bih  = (const float*)d_in[3];
  const float* bhh  = (const float*)d_in[4];
  const float* Wout = (const float*)d_in[5];
  const float* bout = (const float*)d_in[6];
  float* out = (float*)d_out;

  char* ws = (char*)d_ws;
  float* hbuf = (float*)ws;                 // 2*2*2048 fp32 = 32 KB
  int* root = (int*)(ws + 32768);           // 2048 ints = 8 KB
  int* leaf = (int*)(ws + 40960);           // 16*2048 ints = 128 KB

  hipFuncSetAttribute((const void*)lstm_kernel,
                      hipFuncAttributeMaxDynamicSharedMemorySize, SMEM_MAIN);
  hipFuncSetAttribute((const void*)proj_kernel,
                      hipFuncAttributeMaxDynamicSharedMemorySize, SMEM_PROJ);

  init_kernel<<<128, 256, 0, stream>>>(root, leaf);

  void* args[] = { (void*)&xin, (void*)&Wih, (void*)&Whh, (void*)&bih, (void*)&bhh,
                   (void*)&hbuf, (void*)&root, (void*)&leaf, (void*)&out };
  hipLaunchCooperativeKernel((const void*)lstm_kernel, dim3(NBLK), dim3(NTHR),
                             args, SMEM_MAIN, stream);

  proj_kernel<<<256, 256, SMEM_PROJ, stream>>>(out, Wout, bout);
}

// Round 3
// 11557.491 us; speedup vs baseline: 3.6404x; 3.6404x over previous
//
#include <hip/hip_runtime.h>
#include <stdint.h>

// LSTM, E=2048, B=2, T=2048, ALL I/O float32 (per reference dtypes).
// For t>=1 input==h, so gates = h @ (W_ih+W_hh)^T + (b_ih+b_hh).
// Wc = bf16(W_ih+W_hh) resident in LDS (128.5 KB/CU). 256 blocks (1/CU)
// x 512 threads, cooperative (co-residency only — NO grid barrier).
// h exchange is barrier-free: each h value travels as an 8B atomic chunk
// [tag|payload] through IF$; consumers poll tags (self-validating data).
// No fences / wbl2 / buffer_inv / atomic RMWs anywhere in the hot loop.
// seq written to d_out; projection runs in place afterwards.

#define E 2048
#define NBLK 256
#define NTHR 512
#define WSTRIDE 1028          // dwords per LDS weight row (16B-pad, odd dword phase)
#define SMEM_MAIN 152256
#define SMEM_PROJ 131072

typedef unsigned short u16;
typedef uint32_t u32;
typedef unsigned long long u64;

__device__ __forceinline__ float lo16(u32 u){ return __uint_as_float(u << 16); }
__device__ __forceinline__ float hi16(u32 u){ return __uint_as_float(u & 0xffff0000u); }
__device__ __forceinline__ u16 f2bf(float f){
  u32 u = __float_as_uint(f);
  u32 r = u + 0x7fffu + ((u >> 16) & 1u);   // RNE
  return (u16)(r >> 16);
}
__device__ __forceinline__ u32 pack2(float a, float b){
  return (u32)f2bf(a) | ((u32)f2bf(b) << 16);
}
__device__ __forceinline__ float sigf(float x){ return 1.0f / (1.0f + __expf(-x)); }

// 8 bf16 weights (packed pairs) x fp32 h (LDS) for both batches
__device__ __forceinline__ void accum8(uint4 wq, const float* __restrict__ hp,
                                       float& a0, float& a1){
  float4 p0 = *(const float4*)(hp);
  float4 p1 = *(const float4*)(hp + 4);
  float4 q0 = *(const float4*)(hp + 2048);
  float4 q1 = *(const float4*)(hp + 2052);
  float w0 = lo16(wq.x), w1 = hi16(wq.x), w2 = lo16(wq.y), w3 = hi16(wq.y);
  float w4 = lo16(wq.z), w5 = hi16(wq.z), w6 = lo16(wq.w), w7 = hi16(wq.w);
  a0 = fmaf(w0, p0.x, a0); a0 = fmaf(w1, p0.y, a0);
  a0 = fmaf(w2, p0.z, a0); a0 = fmaf(w3, p0.w, a0);
  a0 = fmaf(w4, p1.x, a0); a0 = fmaf(w5, p1.y, a0);
  a0 = fmaf(w6, p1.z, a0); a0 = fmaf(w7, p1.w, a0);
  a1 = fmaf(w0, q0.x, a1); a1 = fmaf(w1, q0.y, a1);
  a1 = fmaf(w2, q0.z, a1); a1 = fmaf(w3, q0.w, a1);
  a1 = fmaf(w4, q1.x, a1); a1 = fmaf(w5, q1.y, a1);
  a1 = fmaf(w6, q1.z, a1); a1 = fmaf(w7, q1.w, a1);
}

// 8 fp32 weights x fp32 h (t==0 path, full precision)
__device__ __forceinline__ void accum8f(float4 w0v, float4 w1v,
                                        const float* __restrict__ hp,
                                        float& a0, float& a1){
  float4 p0 = *(const float4*)(hp);
  float4 p1 = *(const float4*)(hp + 4);
  float4 q0 = *(const float4*)(hp + 2048);
  float4 q1 = *(const float4*)(hp + 2052);
  a0 = fmaf(w0v.x, p0.x, a0); a0 = fmaf(w0v.y, p0.y, a0);
  a0 = fmaf(w0v.z, p0.z, a0); a0 = fmaf(w0v.w, p0.w, a0);
  a0 = fmaf(w1v.x, p1.x, a0); a0 = fmaf(w1v.y, p1.y, a0);
  a0 = fmaf(w1v.z, p1.z, a0); a0 = fmaf(w1v.w, p1.w, a0);
  a1 = fmaf(w0v.x, q0.x, a1); a1 = fmaf(w0v.y, q0.y, a1);
  a1 = fmaf(w0v.z, q0.z, a1); a1 = fmaf(w0v.w, q0.w, a1);
  a1 = fmaf(w1v.x, q1.x, a1); a1 = fmaf(w1v.y, q1.y, a1);
  a1 = fmaf(w1v.z, q1.z, a1); a1 = fmaf(w1v.w, q1.w, a1);
}

__global__ void __launch_bounds__(NTHR, 1) lstm_kernel(
    const float* __restrict__ xin, const float* __restrict__ Wih,
    const float* __restrict__ Whh, const float* __restrict__ bih,
    const float* __restrict__ bhh, u64* __restrict__ chk,
    float* __restrict__ seqout)
{
  extern __shared__ char smem[];
  u32*   wlds = (u32*)smem;                    // 32 rows x 1028 dw = 131584 B
  float* hlds = (float*)(smem + 131584);       // h (or x) fp32 [2][2048] = 16384 B
  float* pls  = (float*)(smem + 147968);       // partials [8][64][2] = 4096 B
  float* bias = (float*)(smem + 152064);       // [32]
  float* cst  = (float*)(smem + 152192);       // c state [2][8]

  const int tid = threadIdx.x;
  const int blk = blockIdx.x;
  const int e0  = blk << 3;                    // this block owns h elems e0..e0+7

  // ---- build Wc = bf16(Wih + Whh) into LDS: row r = gate*8 + eoff ----
  for (int idx = tid; idx < 8192; idx += NTHR){
    const int rr = idx >> 8;
    const int kc = (idx & 255) << 3;
    const int grow = ((rr >> 3) << 11) + e0 + (rr & 7);
    const float* pa = Wih + (size_t)grow * E + kc;
    const float* pb = Whh + (size_t)grow * E + kc;
    float4 a0 = *(const float4*)(pa);
    float4 a1 = *(const float4*)(pa + 4);
    float4 b0 = *(const float4*)(pb);
    float4 b1 = *(const float4*)(pb + 4);
    uint4 o;
    o.x = pack2(a0.x + b0.x, a0.y + b0.y);
    o.y = pack2(a0.z + b0.z, a0.w + b0.w);
    o.z = pack2(a1.x + b1.x, a1.y + b1.y);
    o.w = pack2(a1.z + b1.z, a1.w + b1.w);
    *(uint4*)(wlds + rr * WSTRIDE + (kc >> 1)) = o;
  }
  if (tid < 32){
    const int grow = ((tid >> 3) << 11) + e0 + (tid & 7);
    bias[tid] = bih[grow] + bhh[grow];
  }
  if (tid < 16) cst[tid] = 0.0f;
  for (int i = tid; i < 2 * E; i += NTHR) hlds[i] = xin[i];  // x for t=0
  __syncthreads();

  const int lane = tid & 63;
  const int wv   = tid >> 6;                   // wave 0..7
  const int r    = lane & 31;                  // row within block (gate*8+eoff)
  const int kh   = lane >> 5;                  // k-half within wave
  const int kbase = ((wv << 1) + kh) << 7;     // 16 k-slices x 128
  const int grow_r = ((r >> 3) << 11) + e0 + (r & 7);

  // consumer poll-slot mapping: chunk c -> hlds[((c>>3)&1)*2048 + (c>>4)*8 + (c&7)]
  int cdst[8];
  #pragma unroll
  for (int k = 0; k < 8; ++k){
    const int c = tid + (k << 9);
    cdst[k] = (((c >> 3) & 1) << 11) + ((c >> 4) << 3) + (c & 7);
  }

  for (int t = 0; t < 2048; ++t){
    float a0 = 0.0f, a1 = 0.0f;
    if (t == 0){                               // step 0: x @ W_ih^T (h=0), f32 weights
      const float* wsrc = Wih + (size_t)grow_r * E + kbase;
      const float* hp = hlds + kbase;
      #pragma unroll
      for (int c = 0; c < 16; ++c){
        float4 w0v = *(const float4*)(wsrc + (c << 3));
        float4 w1v = *(const float4*)(wsrc + (c << 3) + 4);
        accum8f(w0v, w1v, hp + (c << 3), a0, a1);
      }
    } else {                                   // t>=1: h @ Wc^T from LDS (bf16)
      const u32* wrow = wlds + r * WSTRIDE + (kbase >> 1);
      const float* hp = hlds + kbase;
      #pragma unroll
      for (int c = 0; c < 16; ++c){
        uint4 wq = *(const uint4*)(wrow + (c << 2));
        accum8(wq, hp + (c << 3), a0, a1);
      }
    }
    *(float2*)(pls + (((wv << 6) + lane) << 1)) = make_float2(a0, a1);
    __syncthreads();                           // (A) partials ready; hlds free

    if (wv == 0){                              // wave 0: reduce + state update
      const int b = kh;
      float s = bias[r];
      #pragma unroll
      for (int ww = 0; ww < 8; ++ww){
        s += pls[(((ww << 6) + r)      << 1) + b]
           + pls[(((ww << 6) + 32 + r) << 1) + b];
      }
      const float gi = s;
      const float gf = __shfl(s, (lane + 8)  & 63, 64);
      const float gg = __shfl(s, (lane + 16) & 63, 64);
      const float go = __shfl(s, (lane + 24) & 63, 64);
      if (r < 8){
        const int ci = (b << 3) + r;
        const float cold = cst[ci];
        const float cn = sigf(gf) * cold + sigf(gi) * tanhf(gg);
        const float hn = sigf(go) * tanhf(cn);
        cst[ci] = cn;
        seqout[(((size_t)b << 11) + (size_t)t) * E + e0 + r] = hn;
        if (t < 2047){                         // fire-and-forget tagged chunk
          const u64 pk = ((u64)(u32)(t + 1) << 32) | (u64)__float_as_uint(hn);
          __hip_atomic_store(&chk[(((t + 1) & 1) << 12) + (blk << 4) + (b << 3) + r],
                             pk, __ATOMIC_RELAXED, __HIP_MEMORY_SCOPE_AGENT);
        }
      }
    }

    if (t < 2047){                             // all waves: poll next h into LDS
      const u64* src = chk + (((t + 1) & 1) << 12);
      const u32 tag = (u32)(t + 1);
      u64 u[8];
      #pragma unroll
      for (int k = 0; k < 8; ++k)
        u[k] = __hip_atomic_load(&src[tid + (k << 9)],
                                 __ATOMIC_RELAXED, __HIP_MEMORY_SCOPE_AGENT);
      int pend = 0xFF;
      while (pend){
        #pragma unroll
        for (int k = 0; k < 8; ++k){
          if (pend & (1 << k)){
            if ((u32)(u[k] >> 32) == tag){
              hlds[cdst[k]] = __uint_as_float((u32)u[k]);
              pend &= ~(1 << k);
            }
          }
        }
        if (pend){
          #pragma unroll
          for (int k = 0; k < 8; ++k)
            if (pend & (1 << k))
              u[k] = __hip_atomic_load(&src[tid + (k << 9)],
                                       __ATOMIC_RELAXED, __HIP_MEMORY_SCOPE_AGENT);
          __builtin_amdgcn_s_sleep(1);
        }
      }
      __syncthreads();                         // (C) hlds complete for step t+1
    }
  }
}

// In-place projection: out[row][n] = sum_k h[row][k]*Wout[n][k] + bout[n].
// Block owns 16 rows, staged to LDS first. 2 n-columns per pass halves the
// LDS read instruction count (proj is LDS-issue-bound at 1 wave/SIMD).
__global__ void __launch_bounds__(256, 1) proj_kernel(
    float* __restrict__ io, const float* __restrict__ Wout,
    const float* __restrict__ bout)
{
  extern __shared__ char smem[];
  float* alds = (float*)smem;                  // 16 x 2048 fp32 = 131072 B
  const int tid = threadIdx.x;
  const size_t rbase = (size_t)blockIdx.x * 16 * E;

  for (int idx = tid; idx < 8192; idx += 256){
    float4 v = *(const float4*)(io + rbase + ((size_t)idx << 2));
    *(float4*)(alds + (idx << 2)) = v;
  }
  __syncthreads();

  for (int p = 0; p < 4; ++p){
    const int n0 = (p << 8) + tid;             // column pair: n0, n0+1024
    const int n1 = n0 + 1024;
    const float* wr0 = Wout + (size_t)n0 * E;
    const float* wr1 = Wout + (size_t)n1 * E;
    float acc0[16], acc1[16];
    #pragma unroll
    for (int m = 0; m < 16; ++m){ acc0[m] = 0.0f; acc1[m] = 0.0f; }
    for (int kc = 0; kc < 256; ++kc){
      const float4 a0v = *(const float4*)(wr0 + (kc << 3));
      const float4 a1v = *(const float4*)(wr0 + (kc << 3) + 4);
      const float4 b0v = *(const float4*)(wr1 + (kc << 3));
      const float4 b1v = *(const float4*)(wr1 + (kc << 3) + 4);
      const float* ap = alds + (kc << 3);
      #pragma unroll
      for (int m = 0; m < 16; ++m){
        const float* a = ap + (m << 11);
        float4 x0 = *(const float4*)(a);
        float4 x1 = *(const float4*)(a + 4);
        acc0[m] = fmaf(a0v.x, x0.x, acc0[m]); acc0[m] = fmaf(a0v.y, x0.y, acc0[m]);
        acc0[m] = fmaf(a0v.z, x0.z, acc0[m]); acc0[m] = fmaf(a0v.w, x0.w, acc0[m]);
        acc0[m] = fmaf(a1v.x, x1.x, acc0[m]); acc0[m] = fmaf(a1v.y, x1.y, acc0[m]);
        acc0[m] = fmaf(a1v.z, x1.z, acc0[m]); acc0[m] = fmaf(a1v.w, x1.w, acc0[m]);
        acc1[m] = fmaf(b0v.x, x0.x, acc1[m]); acc1[m] = fmaf(b0v.y, x0.y, acc1[m]);
        acc1[m] = fmaf(b0v.z, x0.z, acc1[m]); acc1[m] = fmaf(b0v.w, x0.w, acc1[m]);
        acc1[m] = fmaf(b1v.x, x1.x, acc1[m]); acc1[m] = fmaf(b1v.y, x1.y, acc1[m]);
        acc1[m] = fmaf(b1v.z, x1.z, acc1[m]); acc1[m] = fmaf(b1v.w, x1.w, acc1[m]);
      }
    }
    const float bo0 = bout[n0];
    const float bo1 = bout[n1];
    #pragma unroll
    for (int m = 0; m < 16; ++m){
      io[rbase + ((size_t)m << 11) + n0] = acc0[m] + bo0;
      io[rbase + ((size_t)m << 11) + n1] = acc1[m] + bo1;
    }
  }
}

extern "C" void kernel_launch(void* const* d_in, const int* in_sizes, int n_in,
                              void* d_out, int out_size, void* d_ws, size_t ws_size,
                              hipStream_t stream)
{
  const float* xin  = (const float*)d_in[0];
  const float* Wih  = (const float*)d_in[1];
  const float* Whh  = (const float*)d_in[2];
  const float* bih  = (const float*)d_in[3];
  const float* bhh  = (const float*)d_in[4];
  const float* Wout = (const float*)d_in[5];
  const float* bout = (const float*)d_in[6];
  float* out = (float*)d_out;

  // chunk buffer: 2 parities x 4096 chunks x 8 B = 64 KB.
  // Poison 0xAAAAAAAA is never a valid tag (tags are 1..2047) -> no init pass.
  u64* chk = (u64*)d_ws;

  hipFuncSetAttribute((const void*)lstm_kernel,
                      hipFuncAttributeMaxDynamicSharedMemorySize, SMEM_MAIN);
  hipFuncSetAttribute((const void*)proj_kernel,
                      hipFuncAttributeMaxDynamicSharedMemorySize, SMEM_PROJ);

  void* args[] = { (void*)&xin, (void*)&Wih, (void*)&Whh, (void*)&bih, (void*)&bhh,
                   (void*)&chk, (void*)&out };
  hipLaunchCooperativeKernel((const void*)lstm_kernel, dim3(NBLK), dim3(NTHR),
                             args, SMEM_MAIN, stream);

  proj_kernel<<<256, 256, SMEM_PROJ, stream>>>(out, Wout, bout);
}